// Round 4
// baseline (107.244 us; speedup 1.0000x reference)
//
#include <hip/hip_runtime.h>

// u_dot_v edge scoring: score[e] = dot(h[src[e]], h[dst[e]]), D=64.
//
// History: fp32 gather 65us (L2-miss BW bound) -> bf16 36us -> int8 ~30us.
// int8 halved bytes but only gained 17% => edge kernel is latency/MLP-bound,
// not BW-bound. This round: 1 thread = 1 edge, fully unrolled: 8 independent
// 16B row loads + idx + scales all in flight per thread, zero shuffles,
// no redundant per-lane idx/scale loads. Line-level traffic unchanged
// (64B row = 1 line), so any gain is pure latency-hiding.

#define D_FEAT 64

// ---- Pass 1: per-row max-abs int8 quantization (16 lanes/row) ----
__global__ __launch_bounds__(256) void quant_kernel(
    const float* __restrict__ h,
    unsigned int* __restrict__ q,     // [n_rows*16] packed 4x int8
    float* __restrict__ rscale,       // [n_rows] = maxabs/127
    int n_rows)
{
    int tid  = blockIdx.x * blockDim.x + threadIdx.x;
    int row  = tid >> 4;
    int lane = tid & 15;
    if (row >= n_rows) return;

    const float4* p = (const float4*)(h + (size_t)row * D_FEAT);
    float4 v = p[lane];

    float m = fmaxf(fmaxf(fabsf(v.x), fabsf(v.y)),
                    fmaxf(fabsf(v.z), fabsf(v.w)));
    m = fmaxf(m, __shfl_xor(m, 1, 64));
    m = fmaxf(m, __shfl_xor(m, 2, 64));
    m = fmaxf(m, __shfl_xor(m, 4, 64));
    m = fmaxf(m, __shfl_xor(m, 8, 64));

    float s = (m > 0.0f) ? 127.0f / m : 0.0f;
    int q0 = (int)rintf(v.x * s);
    int q1 = (int)rintf(v.y * s);
    int q2 = (int)rintf(v.z * s);
    int q3 = (int)rintf(v.w * s);
    unsigned int packed = ((unsigned)q0 & 0xFFu)
                        | (((unsigned)q1 & 0xFFu) << 8)
                        | (((unsigned)q2 & 0xFFu) << 16)
                        | (((unsigned)q3 & 0xFFu) << 24);
    q[(size_t)row * 16 + lane] = packed;
    if (lane == 0) rscale[row] = m * (1.0f / 127.0f);
}

#if defined(__has_builtin)
#  if __has_builtin(__builtin_amdgcn_sdot4)
#    define HAVE_SDOT4 1
#  endif
#endif

static __device__ __forceinline__ int dp4(unsigned int a, unsigned int b, int c) {
#ifdef HAVE_SDOT4
    return __builtin_amdgcn_sdot4((int)a, (int)b, c, false);
#else
    c += (int)(signed char)( a        & 0xFFu) * (int)(signed char)( b        & 0xFFu);
    c += (int)(signed char)((a >> 8)  & 0xFFu) * (int)(signed char)((b >> 8)  & 0xFFu);
    c += (int)(signed char)((a >> 16) & 0xFFu) * (int)(signed char)((b >> 16) & 0xFFu);
    c += (int)(signed char)( a >> 24         ) * (int)(signed char)( b >> 24         );
    return c;
#endif
}

// ---- Pass 2: 1 thread per edge, 8x16B row loads fully in flight ----
__global__ __launch_bounds__(256) void edge_dot_q8_kernel(
    const uint4* __restrict__ q,          // 4 x uint4 (64B) per row
    const float* __restrict__ rscale,
    const int* __restrict__ src,
    const int* __restrict__ dst,
    float* __restrict__ out,
    int n_edges)
{
    int e = blockIdx.x * blockDim.x + threadIdx.x;
    if (e >= n_edges) return;

    int s = src[e];
    int d = dst[e];

    const uint4* pu = q + (size_t)s * 4;
    const uint4* pv = q + (size_t)d * 4;

    // All 8 row loads + 2 scale loads independent -> max MLP per thread.
    uint4 a0 = pu[0];
    uint4 a1 = pu[1];
    uint4 a2 = pu[2];
    uint4 a3 = pu[3];
    uint4 b0 = pv[0];
    uint4 b1 = pv[1];
    uint4 b2 = pv[2];
    uint4 b3 = pv[3];
    float su = rscale[s];
    float sv = rscale[d];

    int acc = 0;
    acc = dp4(a0.x, b0.x, acc);
    acc = dp4(a0.y, b0.y, acc);
    acc = dp4(a0.z, b0.z, acc);
    acc = dp4(a0.w, b0.w, acc);
    acc = dp4(a1.x, b1.x, acc);
    acc = dp4(a1.y, b1.y, acc);
    acc = dp4(a1.z, b1.z, acc);
    acc = dp4(a1.w, b1.w, acc);
    acc = dp4(a2.x, b2.x, acc);
    acc = dp4(a2.y, b2.y, acc);
    acc = dp4(a2.z, b2.z, acc);
    acc = dp4(a2.w, b2.w, acc);
    acc = dp4(a3.x, b3.x, acc);
    acc = dp4(a3.y, b3.y, acc);
    acc = dp4(a3.z, b3.z, acc);
    acc = dp4(a3.w, b3.w, acc);

    out[e] = (float)acc * (su * sv);
}

// ---- Fallback (ws too small): fp32 path, 16 lanes/edge ----
__global__ __launch_bounds__(256) void edge_dot_f32_kernel(
    const float* __restrict__ h,
    const int* __restrict__ src,
    const int* __restrict__ dst,
    float* __restrict__ out,
    int n_edges)
{
    int tid  = blockIdx.x * blockDim.x + threadIdx.x;
    int edge = tid >> 4;
    int lane = tid & 15;
    if (edge >= n_edges) return;
    int s = src[edge];
    int d = dst[edge];
    const float4* hu = (const float4*)(h + (size_t)s * D_FEAT);
    const float4* hv = (const float4*)(h + (size_t)d * D_FEAT);
    float4 a = hu[lane];
    float4 b = hv[lane];
    float p = a.x * b.x + a.y * b.y + a.z * b.z + a.w * b.w;
    p += __shfl_xor(p, 1, 64);
    p += __shfl_xor(p, 2, 64);
    p += __shfl_xor(p, 4, 64);
    p += __shfl_xor(p, 8, 64);
    if (lane == 0) out[edge] = p;
}

extern "C" void kernel_launch(void* const* d_in, const int* in_sizes, int n_in,
                              void* d_out, int out_size, void* d_ws, size_t ws_size,
                              hipStream_t stream)
{
    const float* h  = (const float*)d_in[0];
    const int* src  = (const int*)d_in[1];
    const int* dst  = (const int*)d_in[2];
    float* out      = (float*)d_out;

    int n_h     = in_sizes[0];           // 6,400,000 floats
    int n_edges = in_sizes[1];           // 1,000,000
    int n_rows  = n_h / D_FEAT;          // 100,000

    size_t q_bytes = (size_t)n_rows * D_FEAT;          // 6.4 MB int8
    size_t need    = q_bytes + (size_t)n_rows * 4;     // + scales

    if (ws_size >= need && (n_h % D_FEAT) == 0) {
        unsigned int* q = (unsigned int*)d_ws;
        float* rscale   = (float*)((char*)d_ws + q_bytes);

        int block = 256;
        int qt = n_rows * 16;
        quant_kernel<<<(qt + block - 1) / block, block, 0, stream>>>(
            h, q, rscale, n_rows);

        edge_dot_q8_kernel<<<(n_edges + block - 1) / block, block, 0, stream>>>(
            (const uint4*)q, rscale, src, dst, out, n_edges);
    } else {
        int total = n_edges * 16;
        int block = 256;
        edge_dot_f32_kernel<<<(total + block - 1) / block, block, 0, stream>>>(
            h, src, dst, out, n_edges);
    }
}